// Round 8
// baseline (721.471 us; speedup 1.0000x reference)
//
#include <hip/hip_runtime.h>
#include <hip/hip_cooperative_groups.h>
#include <math.h>

namespace cg = cooperative_groups;

#define NQ 131072
#define MN 8192
#define DEPTHT 16
#define EPSD 1e-6f
#define BIGD 1e9f
#define NBLK 2176           // 2176*64 = 139264 = NQ + MN rows, 1 wave/block

// ---------------------------------------------------------------------------
// R17. Journal (do not retry):
//  R10 convoy barriers 77.9 | R11 w3->LDS 80.0 | R12 bank fix neutral
//  R13 half-grid: mlp PER-WAVE LATENCY bound (grid-independent 71.8)
//  R14 readlane 114 | R15 VMEM bcast 224 (spill) -> mlp FROZEN at R0 dag
//  R16 de-LDS traverse + prob2 inline: neutral (staging/prob2 never the cost)
//  Accounting after R16: total - mlp - transpose ~ 89us, yet traverse never
//  in top-5 (<69.5) and every model says <=10us. R13 says dispatch
//  boundaries are expensive. R17: ONE cooperative dispatch (transpose ->
//  grid.sync -> mlp -> grid.sync -> traverse). Queries keep their mlp output
//  in REGISTERS across the sync (qx round-trip deleted). Node blocks
//  (2048..2175) idle in phase 2. FP dag bit-identical everywhere (R5
//  contract). Fused kernel = guaranteed top-1 counter row next round.
// ---------------------------------------------------------------------------
__global__ __launch_bounds__(64, 3) void fused_kernel(
    const float* __restrict__ x, const float* __restrict__ nd,
    const float* __restrict__ cls,
    const float* __restrict__ W1, const float* __restrict__ b1,
    const float* __restrict__ W2, const float* __restrict__ b2,
    const float* __restrict__ W3, const float* __restrict__ b3,
    const float* __restrict__ W4, const float* __restrict__ b4,
    float* __restrict__ w2t, float* __restrict__ embf,
    float* __restrict__ out)
{
    cg::grid_group grid = cg::this_grid();
    const int r = blockIdx.x * 64 + threadIdx.x;    // row / query id

    // ---- phase 0: transpose W2 [k][j] -> w2t [j][k] ----
    if (r < 100 * 100) {
        const int k = r / 100, j = r - k * 100;
        w2t[j * 100 + k] = W2[r];
    }
    grid.sync();

    // ---- phase 1: MLP 2->100->100->30->2, one row per thread (VERBATIM R0;
    //      weights all s_load uniform; do not touch the dag) ----
    const float2 xi = (r < NQ) ? ((const float2*)x)[r]
                               : ((const float2*)nd)[r - NQ];

    float h1[100];
#pragma unroll
    for (int k = 0; k < 100; ++k)
        h1[k] = fmaxf(fmaf(xi.x, W1[k], fmaf(xi.y, W1[100 + k], b1[k])), 0.0f);

    float h3[30];
#pragma unroll
    for (int jj = 0; jj < 30; ++jj) h3[jj] = b3[jj];

    const float* w2 = w2t;
    const float* w3 = W3;
    for (int j = 0; j < 100; ++j) {
        float a0 = 0.0f, a1 = 0.0f;                 // 2 chains: hide FMA latency
#pragma unroll
        for (int k = 0; k < 100; k += 2) {
            a0 = fmaf(h1[k],     w2[k],     a0);    // w2[k]: s_load scalar
            a1 = fmaf(h1[k + 1], w2[k + 1], a1);
        }
        const float h2j = fmaxf(a0 + a1 + b2[j], 0.0f);
#pragma unroll
        for (int jj = 0; jj < 30; ++jj)
            h3[jj] = fmaf(h2j, w3[jj], h3[jj]);     // w3[jj]: s_load scalar
        w2 += 100;
        w3 += 30;
    }

    float o0 = b4[0], o1 = b4[1];
#pragma unroll
    for (int k = 0; k < 30; ++k) {
        const float h = fmaxf(h3[k], 0.0f);
        o0 = fmaf(h, W4[2 * k],     o0);
        o1 = fmaf(h, W4[2 * k + 1], o1);
    }

    // node rows publish emb; query rows KEEP (o0,o1) in registers as qv
    if (r >= NQ) ((float2*)embf)[r - NQ] = make_float2(o0, o1);
    __threadfence();
    grid.sync();

    // ---- phase 2: traversal (query threads only; node blocks 2048..2175
    //      are whole idle blocks -> no intra-wave divergence). VERBATIM R16:
    //      global emb reads, prob2 dag inlined at the stop. ----
    if (r < NQ) {
        const float2 qv = make_float2(o0, o1);
        const float2* emb = (const float2*)embf;
        const float2* cl2 = (const float2*)cls;

        int cur = 0;
        float d0;
        {
            const float2 e0 = emb[0];
            const float dx = e0.x - qv.x + EPSD;
            const float dy = e0.y - qv.y + EPSD;
            d0 = sqrtf(dx * dx + dy * dy);
        }
        float prob = 0.0f, out0 = 0.0f, out1 = 0.0f;
        bool done = false;

        for (int t = 0; t < DEPTHT; ++t) {
            if (__all(done)) break;
            if (!done) {
                const int base = 8 * cur + 1;

                float dc[8];
#pragma unroll
                for (int j = 0; j < 8; ++j) {
                    const int c = base + j;
                    const bool v = c < MN;
                    const float2 e = emb[v ? c : 0];
                    const float dx = e.x - qv.x + EPSD;
                    const float dy = e.y - qv.y + EPSD;
                    dc[j] = v ? sqrtf(dx * dx + dy * dy) : BIGD;
                }

                // argmax(log_softmax(-d)) == first argmin(d)
                float dmin = d0;
                int amax = 0;
#pragma unroll
                for (int j = 0; j < 8; ++j)
                    if (dc[j] < dmin) { dmin = dc[j]; amax = j + 1; }

                float s = expf(dmin - d0);
#pragma unroll
                for (int j = 0; j < 8; ++j) s += expf(dmin - dc[j]);
                const float max_prob = -logf(s);
                // quirk: t==0 adds max_prob twice
                const float prob_new = prob + max_prob + ((t == 0) ? max_prob : 0.0f);

                if (amax == 0) {
                    if (base < MN) {
                        // ---- inline prob2 for node cur (verbatim dag) ----
                        const float2 ei = emb[cur];
                        float d2[8];
                        float m2 = BIGD;
#pragma unroll
                        for (int j = 0; j < 8; ++j) {
                            const int c = base + j;
                            const bool v = c < MN;
                            const float2 ec = emb[v ? c : 0];
                            const float dx = ei.x - ec.x + EPSD;
                            const float dy = ei.y - ec.y + EPSD;
                            d2[j] = v ? sqrtf(dx * dx + dy * dy) : BIGD;
                            m2 = fminf(m2, d2[j]);
                        }
                        float s2 = 0.0f, mix0 = 0.0f, mix1 = 0.0f;
#pragma unroll
                        for (int j = 0; j < 8; ++j) {
                            const float w = expf(m2 - d2[j]);   // exactly 0 for pads
                            s2 += w;
                            const int c = base + j;
                            if (c < MN) {
                                const float2 cv = cl2[c];
                                mix0 = fmaf(w, cv.x, mix0);
                                mix1 = fmaf(w, cv.y, mix1);
                            }
                        }
                        mix0 /= s2;
                        mix1 /= s2;
                        out0 = prob_new + logf(fmaxf(mix0, 1e-30f));
                        out1 = prob_new + logf(fmaxf(mix1, 1e-30f));
                    } else {                          // leaf
                        out0 = prob_new;
                        out1 = prob_new;
                    }
                    done = true;
                } else {
                    cur  = base + amax - 1;
                    d0   = dmin;                      // child dist == next d0
                    prob = prob_new;
                }
            }
        }

        ((float2*)out)[r] = make_float2(out0, out1);
    }
}

// ---------------------------------------------------------------------------
// Fallback path (R7 kernels, regular launches) in case cooperative launch
// is rejected at capture time. Unused when the fused path works.
// ---------------------------------------------------------------------------
__global__ __launch_bounds__(256) void transpose_w2(
    const float* __restrict__ W2, float* __restrict__ W2T)
{
    const int i = blockIdx.x * 256 + threadIdx.x;
    if (i < 100 * 100) {
        const int k = i / 100, j = i - k * 100;
        W2T[j * 100 + k] = W2[i];
    }
}

__global__ __launch_bounds__(64, 2) void mlp_kernel(
    const float* __restrict__ x, const float* __restrict__ nd,
    const float* __restrict__ W1, const float* __restrict__ b1,
    const float* __restrict__ W2T, const float* __restrict__ b2,
    const float* __restrict__ W3, const float* __restrict__ b3,
    const float* __restrict__ W4, const float* __restrict__ b4,
    float* __restrict__ outv)
{
    const int r = blockIdx.x * 64 + threadIdx.x;
    const float2 xi = (r < NQ) ? ((const float2*)x)[r]
                               : ((const float2*)nd)[r - NQ];
    float h1[100];
#pragma unroll
    for (int k = 0; k < 100; ++k)
        h1[k] = fmaxf(fmaf(xi.x, W1[k], fmaf(xi.y, W1[100 + k], b1[k])), 0.0f);
    float h3[30];
#pragma unroll
    for (int jj = 0; jj < 30; ++jj) h3[jj] = b3[jj];
    const float* w2 = W2T;
    const float* w3 = W3;
    for (int j = 0; j < 100; ++j) {
        float a0 = 0.0f, a1 = 0.0f;
#pragma unroll
        for (int k = 0; k < 100; k += 2) {
            a0 = fmaf(h1[k],     w2[k],     a0);
            a1 = fmaf(h1[k + 1], w2[k + 1], a1);
        }
        const float h2j = fmaxf(a0 + a1 + b2[j], 0.0f);
#pragma unroll
        for (int jj = 0; jj < 30; ++jj)
            h3[jj] = fmaf(h2j, w3[jj], h3[jj]);
        w2 += 100;
        w3 += 30;
    }
    float o0 = b4[0], o1 = b4[1];
#pragma unroll
    for (int k = 0; k < 30; ++k) {
        const float h = fmaxf(h3[k], 0.0f);
        o0 = fmaf(h, W4[2 * k],     o0);
        o1 = fmaf(h, W4[2 * k + 1], o1);
    }
    ((float2*)outv)[r] = make_float2(o0, o1);
}

__global__ __launch_bounds__(256) void traverse_kernel(
    const float* __restrict__ qx, const float2* __restrict__ emb,
    const float2* __restrict__ cls, float* __restrict__ out)
{
    const int qi = blockIdx.x * 256 + threadIdx.x;
    const float2 qv = ((const float2*)qx)[qi];
    int cur = 0;
    float d0;
    {
        const float2 e0 = emb[0];
        const float dx = e0.x - qv.x + EPSD;
        const float dy = e0.y - qv.y + EPSD;
        d0 = sqrtf(dx * dx + dy * dy);
    }
    float prob = 0.0f, out0 = 0.0f, out1 = 0.0f;
    bool done = false;
    for (int t = 0; t < DEPTHT; ++t) {
        if (__all(done)) break;
        if (!done) {
            const int base = 8 * cur + 1;
            float dc[8];
#pragma unroll
            for (int j = 0; j < 8; ++j) {
                const int c = base + j;
                const bool v = c < MN;
                const float2 e = emb[v ? c : 0];
                const float dx = e.x - qv.x + EPSD;
                const float dy = e.y - qv.y + EPSD;
                dc[j] = v ? sqrtf(dx * dx + dy * dy) : BIGD;
            }
            float dmin = d0;
            int amax = 0;
#pragma unroll
            for (int j = 0; j < 8; ++j)
                if (dc[j] < dmin) { dmin = dc[j]; amax = j + 1; }
            float s = expf(dmin - d0);
#pragma unroll
            for (int j = 0; j < 8; ++j) s += expf(dmin - dc[j]);
            const float max_prob = -logf(s);
            const float prob_new = prob + max_prob + ((t == 0) ? max_prob : 0.0f);
            if (amax == 0) {
                if (base < MN) {
                    const float2 ei = emb[cur];
                    float d2[8];
                    float m2 = BIGD;
#pragma unroll
                    for (int j = 0; j < 8; ++j) {
                        const int c = base + j;
                        const bool v = c < MN;
                        const float2 ec = emb[v ? c : 0];
                        const float dx = ei.x - ec.x + EPSD;
                        const float dy = ei.y - ec.y + EPSD;
                        d2[j] = v ? sqrtf(dx * dx + dy * dy) : BIGD;
                        m2 = fminf(m2, d2[j]);
                    }
                    float s2 = 0.0f, mix0 = 0.0f, mix1 = 0.0f;
#pragma unroll
                    for (int j = 0; j < 8; ++j) {
                        const float w = expf(m2 - d2[j]);
                        s2 += w;
                        const int c = base + j;
                        if (c < MN) {
                            const float2 cv = cls[c];
                            mix0 = fmaf(w, cv.x, mix0);
                            mix1 = fmaf(w, cv.y, mix1);
                        }
                    }
                    mix0 /= s2;
                    mix1 /= s2;
                    out0 = prob_new + logf(fmaxf(mix0, 1e-30f));
                    out1 = prob_new + logf(fmaxf(mix1, 1e-30f));
                } else {
                    out0 = prob_new;
                    out1 = prob_new;
                }
                done = true;
            } else {
                cur  = base + amax - 1;
                d0   = dmin;
                prob = prob_new;
            }
        }
    }
    ((float2*)out)[qi] = make_float2(out0, out1);
}

// ---------------------------------------------------------------------------
extern "C" void kernel_launch(void* const* d_in, const int* in_sizes, int n_in,
                              void* d_out, int out_size, void* d_ws, size_t ws_size,
                              hipStream_t stream)
{
    const float* x   = (const float*)d_in[0];
    const float* nd  = (const float*)d_in[1];
    const float* cls = (const float*)d_in[2];
    // d_in[3] (children) unused: complete 8-ary tree, child = 8i+1+j if <8192
    const float* W1 = (const float*)d_in[4];
    const float* b1 = (const float*)d_in[5];
    const float* W2 = (const float*)d_in[6];
    const float* b2 = (const float*)d_in[7];
    const float* W3 = (const float*)d_in[8];
    const float* b3 = (const float*)d_in[9];
    const float* W4 = (const float*)d_in[10];
    const float* b4 = (const float*)d_in[11];

    float* ws   = (float*)d_ws;
    float* w2t  = ws;                        // [100][100]
    float* embf = ws + 100 * 100;            // [MN][2]
    float* qx   = embf + 2 * MN;             // [NQ][2] (fallback only)
    float* outp = (float*)d_out;

    void* args[] = { (void*)&x, (void*)&nd, (void*)&cls,
                     (void*)&W1, (void*)&b1, (void*)&W2, (void*)&b2,
                     (void*)&W3, (void*)&b3, (void*)&W4, (void*)&b4,
                     (void*)&w2t, (void*)&embf, (void*)&outp };

    hipError_t err = hipLaunchCooperativeKernel(
        (const void*)fused_kernel, dim3(NBLK), dim3(64), args, 0, stream);

    if (err != hipSuccess) {
        // fallback: R7 3-dispatch path
        transpose_w2<<<40, 256, 0, stream>>>(W2, w2t);
        mlp_kernel<<<NBLK, 64, 0, stream>>>(
            x, nd, W1, b1, w2t, b2, W3, b3, W4, b4, qx);
        traverse_kernel<<<NQ / 256, 256, 0, stream>>>(
            qx + 0, (const float2*)(qx + 2 * NQ), (const float2*)cls, outp);
    }
}

// Round 9
// 396.600 us; speedup vs baseline: 1.8191x; 1.8191x over previous
//
#include <hip/hip_runtime.h>
#include <math.h>

#define NQ 131072
#define MN 8192
#define NINT 1024          // internal nodes: 8*i+1 < 8192 -> i <= 1023
#define DEPTHT 16
#define EPSD 1e-6f
#define BIGD 1e9f

// ---------------------------------------------------------------------------
// R18. Journal (do not retry):
//  R10 convoy 77.9 | R11 w3->LDS+SMEM mix 80.0 | R12 bank fix neutral
//  R13 half-grid: mlp PER-WAVE LATENCY bound | R14 readlane 114 (SGPR hazard)
//  R15/R6 VMEM bcast 224: INVALID TEST — missing launch_bounds min-waves ->
//    84-VGPR cap -> scratch spill. R17 coop fusion 643: grid.sync liveness
//    spilled h1; BUT one-dispatch graph still had ~78us non-kernel time ->
//    PROOF: ~78us is constant harness overhead; traverse ~8us all along.
//  Real budget: mlp 70 + traverse ~8 + transpose 1.3. Lever = mlp only.
//  R18 mlp transport: lane-distributed global_load_dwordx4 (1 instr fetches
//  the whole 400B row) -> single-wave LDS double buffer -> k-loop consumes
//  via WAVE-UNIFORM ds_read_b128 broadcasts (25+8/row, in-order lgkmcnt,
//  no SMEM in loop, no barriers: 1 wave/block). Prior "LDS 98us" was
//  per-element b32 reads (130/row) — this is 33/row vectorized.
//  FMA order bit-identical (R15's float4 a0/a1 pattern, which PASSED).
// ---------------------------------------------------------------------------

// ---------------------------------------------------------------------------
// Kernel 0: W2 [k][j] -> W2T [j][k] (rows 100 floats, 400B, 16B-aligned);
//           W3 [j][30] -> W3P [j][32] (padded rows for aligned float4).
// ---------------------------------------------------------------------------
__global__ __launch_bounds__(256) void transpose_w2(
    const float* __restrict__ W2, float* __restrict__ W2T,
    const float* __restrict__ W3, float* __restrict__ W3P)
{
    const int i = blockIdx.x * 256 + threadIdx.x;
    if (i < 100 * 100) {
        const int k = i / 100, j = i - k * 100;
        W2T[j * 100 + k] = W2[i];
    } else if (i < 100 * 100 + 100 * 32) {
        const int t = i - 100 * 100;
        const int jj = t >> 5, kk = t & 31;
        W3P[t] = (kk < 30) ? W3[jj * 30 + kk] : 0.0f;
    }
}

// ---------------------------------------------------------------------------
// Kernel 1: MLP 2 -> 100 -> 100 -> 30 -> 2, one row per thread.
// ---------------------------------------------------------------------------
__global__ __launch_bounds__(64, 2) void mlp_kernel(
    const float* __restrict__ x, const float* __restrict__ nd,
    const float* __restrict__ W1, const float* __restrict__ b1,
    const float* __restrict__ W2T, const float* __restrict__ b2,
    const float* __restrict__ W3P, const float* __restrict__ b3,
    const float* __restrict__ W4, const float* __restrict__ b4,
    float* __restrict__ outv)
{
    // single wave per block: no __syncthreads needed, LDS private to wave.
    __shared__ float4 sw[2][33];    // [slot][0..24 w2row | 25..32 w3row]
    __shared__ float4 sb2[25];      // b2, 100 floats

    const int lane = threadIdx.x;
    const int r = blockIdx.x * 64 + lane;           // 2176*64 = 139264 exact
    const float2 xi = (r < NQ) ? ((const float2*)x)[r]
                               : ((const float2*)nd)[r - NQ];

    const bool lw2 = (lane < 25);                   // w2-row loader lanes
    const int  l8  = lane - 32;
    const bool lw3 = (l8 >= 0 && l8 < 8);           // w3-row loader lanes

    if (lw2) sb2[lane] = ((const float4*)b2)[lane]; // stage b2 once

    // ---- layer 1: h1[100] (constant indices only; verbatim R0) ----
    float h1[100];
#pragma unroll
    for (int k = 0; k < 100; ++k)
        h1[k] = fmaxf(fmaf(xi.x, W1[k], fmaf(xi.y, W1[100 + k], b1[k])), 0.0f);

    // ---- prologue: row 0 -> slot 0 ----
    {
        float4 t0 = make_float4(0, 0, 0, 0), t1 = make_float4(0, 0, 0, 0);
        if (lw2) t0 = ((const float4*)W2T)[lane];
        if (lw3) t1 = ((const float4*)W3P)[l8];
        if (lw2) sw[0][lane] = t0;
        if (lw3) sw[0][25 + l8] = t1;
    }

    float h3[30];
#pragma unroll
    for (int jj = 0; jj < 30; ++jj) h3[jj] = b3[jj];

    for (int j = 0; j < 100; ++j) {
        const int cs = j & 1, ns = cs ^ 1;

        // prefetch row j+1 (VMEM latency hides under this row's compute)
        float4 p0 = make_float4(0, 0, 0, 0), p1 = make_float4(0, 0, 0, 0);
        const int jn = (j + 1 < 100) ? j + 1 : 99;   // clamped, unused @ j=99
        if (lw2) p0 = ((const float4*)(W2T + jn * 100))[lane];
        if (lw3) p1 = ((const float4*)(W3P + jn * 32))[l8];

        // consume slot cs: w2 via uniform ds_read_b128 broadcast.
        // FMA order = R15's float4 pattern (PASSED): a0@4c, a1@4c+1,
        // a0@4c+2, a1@4c+3 == R0's alternating k+=2 chains.
        float a0 = 0.0f, a1 = 0.0f;
#pragma unroll
        for (int c = 0; c < 25; ++c) {
            const float4 w = sw[cs][c];
            a0 = fmaf(h1[4 * c + 0], w.x, a0);
            a1 = fmaf(h1[4 * c + 1], w.y, a1);
            a0 = fmaf(h1[4 * c + 2], w.z, a0);
            a1 = fmaf(h1[4 * c + 3], w.w, a1);
        }
        const float4 bq = sb2[j >> 2];
        const float bj = ((j & 3) == 0) ? bq.x :
                         ((j & 3) == 1) ? bq.y :
                         ((j & 3) == 2) ? bq.z : bq.w;
        const float h2j = fmaxf(a0 + a1 + bj, 0.0f);

#pragma unroll
        for (int jj = 0; jj < 30; ++jj) {
            const float4 wv = sw[cs][25 + (jj >> 2)];
            const float w3e = ((jj & 3) == 0) ? wv.x :
                              ((jj & 3) == 1) ? wv.y :
                              ((jj & 3) == 2) ? wv.z : wv.w;
            h3[jj] = fmaf(h2j, w3e, h3[jj]);
        }

        // land prefetched row j+1 into slot ns (ready for next iteration)
        if (lw2) sw[ns][lane] = p0;
        if (lw3) sw[ns][25 + l8] = p1;
    }

    // ---- layer 4: 30 -> 2 (verbatim) ----
    float o0 = b4[0], o1 = b4[1];
#pragma unroll
    for (int k = 0; k < 30; ++k) {
        const float h = fmaxf(h3[k], 0.0f);
        o0 = fmaf(h, W4[2 * k],     o0);
        o1 = fmaf(h, W4[2 * k + 1], o1);
    }
    ((float2*)outv)[r] = make_float2(o0, o1);
}

// ---------------------------------------------------------------------------
// Kernel 2: per-internal-node stop-branch class mixture (query-independent).
// Verbatim (passed every round).
// ---------------------------------------------------------------------------
__global__ __launch_bounds__(256) void prob2_kernel(
    const float2* __restrict__ emb, const float2* __restrict__ cls,
    float2* __restrict__ p2)
{
    const int i = blockIdx.x * 256 + threadIdx.x;   // 0..1023
    const float2 ei = emb[i];
    const int base = 8 * i + 1;

    float d2[8];
    float m2 = BIGD;
#pragma unroll
    for (int j = 0; j < 8; ++j) {
        const int c = base + j;
        const bool v = c < MN;
        const float2 ec = emb[v ? c : 0];
        const float dx = ei.x - ec.x + EPSD;
        const float dy = ei.y - ec.y + EPSD;
        d2[j] = v ? sqrtf(dx * dx + dy * dy) : BIGD;
        m2 = fminf(m2, d2[j]);
    }
    float s2 = 0.0f, mix0 = 0.0f, mix1 = 0.0f;
#pragma unroll
    for (int j = 0; j < 8; ++j) {
        const float w = expf(m2 - d2[j]);   // exactly 0 for pads
        s2 += w;
        const int c = base + j;
        if (c < MN) {
            const float2 cv = cls[c];
            mix0 = fmaf(w, cv.x, mix0);
            mix1 = fmaf(w, cv.y, mix1);
        }
    }
    mix0 /= s2;
    mix1 /= s2;
    p2[i] = make_float2(logf(fmaxf(mix0, 1e-30f)),
                        logf(fmaxf(mix1, 1e-30f)));
}

// ---------------------------------------------------------------------------
// Kernel 3: per-query traversal (R3 best-measured shape: LDS-staged emb with
// bank-decorrelated layout + sp2). d0 carried across steps, verbatim.
// ---------------------------------------------------------------------------
#define SEMB_F (2 * MN + MN / 8)    // 17408 floats = 68 KB

__global__ __launch_bounds__(256) void traverse_kernel(
    const float* __restrict__ qx, const float2* __restrict__ emb,
    const float2* __restrict__ p2g, float* __restrict__ out)
{
    __shared__ float sembf[SEMB_F];  // 68 KB, padded layout
    __shared__ float2 sp2[NINT];     // 8 KB
    {
        for (int c = threadIdx.x; c < MN; c += 256) {   // coalesced 8B/lane
            const float2 e = emb[c];
            const int off = 2 * c + (c >> 3);
            sembf[off]     = e.x;
            sembf[off + 1] = e.y;
        }
        const float4* gp = (const float4*)p2g;
        float4* sp = (float4*)sp2;
#pragma unroll
        for (int t = 0; t < 2; ++t)
            sp[threadIdx.x + 256 * t] = gp[threadIdx.x + 256 * t];
    }
    __syncthreads();

    const int qi = blockIdx.x * 256 + threadIdx.x;  // grid = NQ/256
    const float2 qv = ((const float2*)qx)[qi];

    int cur = 0;
    float d0;
    {
        const float ex = sembf[0], ey = sembf[1];   // node 0 at offset 0
        const float dx = ex - qv.x + EPSD;
        const float dy = ey - qv.y + EPSD;
        d0 = sqrtf(dx * dx + dy * dy);
    }
    float prob = 0.0f, out0 = 0.0f, out1 = 0.0f;
    bool done = false;

    for (int t = 0; t < DEPTHT; ++t) {
        if (__all(done)) break;
        if (!done) {
            const int base = 8 * cur + 1;
            const int boff = 17 * cur + 2;          // float offset of child 0

            float dc[8];
#pragma unroll
            for (int j = 0; j < 8; ++j) {
                const int c = base + j;
                const bool v = c < MN;
                const int off = v ? (boff + 2 * j + (j == 7 ? 1 : 0)) : 0;
                const float ex = sembf[off];
                const float ey = sembf[off + 1];
                const float dx = ex - qv.x + EPSD;
                const float dy = ey - qv.y + EPSD;
                dc[j] = v ? sqrtf(dx * dx + dy * dy) : BIGD;
            }

            // argmax(log_softmax(-d)) == first argmin(d)
            float dmin = d0;
            int amax = 0;
#pragma unroll
            for (int j = 0; j < 8; ++j)
                if (dc[j] < dmin) { dmin = dc[j]; amax = j + 1; }

            float s = expf(dmin - d0);
#pragma unroll
            for (int j = 0; j < 8; ++j) s += expf(dmin - dc[j]);
            const float max_prob = -logf(s);
            // quirk: t==0 adds max_prob twice
            const float prob_new = prob + max_prob + ((t == 0) ? max_prob : 0.0f);

            if (amax == 0) {
                if (base < MN) {                  // internal node
                    const float2 pp = sp2[cur];
                    out0 = prob_new + pp.x;
                    out1 = prob_new + pp.y;
                } else {                          // leaf
                    out0 = prob_new;
                    out1 = prob_new;
                }
                done = true;
            } else {
                cur  = base + amax - 1;
                d0   = dmin;                      // child dist == next d0
                prob = prob_new;
            }
        }
    }

    ((float2*)out)[qi] = make_float2(out0, out1);
}

// ---------------------------------------------------------------------------
extern "C" void kernel_launch(void* const* d_in, const int* in_sizes, int n_in,
                              void* d_out, int out_size, void* d_ws, size_t ws_size,
                              hipStream_t stream)
{
    const float* x   = (const float*)d_in[0];
    const float* nd  = (const float*)d_in[1];
    const float* cls = (const float*)d_in[2];
    // d_in[3] (children) unused: complete 8-ary tree, child = 8i+1+j if <8192
    const float* W1 = (const float*)d_in[4];
    const float* b1 = (const float*)d_in[5];
    const float* W2 = (const float*)d_in[6];
    const float* b2 = (const float*)d_in[7];
    const float* W3 = (const float*)d_in[8];
    const float* b3 = (const float*)d_in[9];
    const float* W4 = (const float*)d_in[10];
    const float* b4 = (const float*)d_in[11];

    float* ws   = (float*)d_ws;
    float* qx   = ws;                        // [NQ][2]
    float* embf = ws + 2 * NQ;               // [MN][2]
    float* p2f  = ws + 2 * (NQ + MN);        // [NINT][2]
    float* w2t  = p2f + 2 * NINT;            // [100][100]
    float* w3p  = w2t + 100 * 100;           // [100][32] padded rows

    transpose_w2<<<52, 256, 0, stream>>>(W2, w2t, W3, w3p);

    mlp_kernel<<<(NQ + MN) / 64, 64, 0, stream>>>(
        x, nd, W1, b1, w2t, b2, w3p, b3, W4, b4, qx);

    prob2_kernel<<<NINT / 256, 256, 0, stream>>>(
        (const float2*)embf, (const float2*)cls, (float2*)p2f);

    traverse_kernel<<<NQ / 256, 256, 0, stream>>>(
        qx, (const float2*)embf, (const float2*)p2f, (float*)d_out);
}

// Round 10
// 157.307 us; speedup vs baseline: 4.5864x; 2.5212x over previous
//
#include <hip/hip_runtime.h>
#include <math.h>

#define NQ 131072
#define MN 8192
#define NINT 1024          // internal nodes: 8*i+1 < 8192 -> i <= 1023
#define DEPTHT 16
#define EPSD 1e-6f
#define BIGD 1e9f

// ---------------------------------------------------------------------------
// R19 = FINAL REVERT to the best measured configuration (R3, 156.0us).
// Complete journal (do not retry):
//  R10 convoy barriers 77.9 | R11 w3->LDS+SMEM mix 80.0 | R12 bank fix neut.
//  R13 half-grid: mlp is PER-WAVE LATENCY bound (71.8 at half grid)
//  R14 readlane 114 (VALU->SGPR hazards) | R15 VMEM bcast 224 (h1 spill)
//  R17 coop fusion 643 (grid.sync liveness spill; proved ~78us constant
//    harness overhead: one-dispatch graph still had total-kernel ~ 78us)
//  R18 LDS-vec transport 318 (VGPR 128 + 15MB scratch: h1 spill again)
//  STRUCTURAL CONCLUSION:
//   - s_load is the only transport that keeps weights in the SCALAR file;
//     all alternatives force h1[100] out of the vector file -> spill.
//   - bit-identity contract forbids k-split/j-split (h3 reassociation) and
//     any precision change; grid is fixed at 2176 waves (1 row/lane) ->
//     2.1 waves/SIMD cannot hide chunked SMEM drains (SGPR file 102 < row
//     100 floats -> no double-buffering).
//   - budget: harness ~78 + mlp ~70 + traverse ~8 + rest ~3 = ~157us,
//     matching every good measurement. This IS the composed floor.
// ---------------------------------------------------------------------------

// ---------------------------------------------------------------------------
// Kernel 0: transpose W2 [k][j] -> W2T [j][k] (contiguous rows for s_load).
// ---------------------------------------------------------------------------
__global__ __launch_bounds__(256) void transpose_w2(
    const float* __restrict__ W2, float* __restrict__ W2T)
{
    const int i = blockIdx.x * 256 + threadIdx.x;
    if (i < 100 * 100) {
        const int k = i / 100, j = i - k * 100;
        W2T[j * 100 + k] = W2[i];
    }
}

// ---------------------------------------------------------------------------
// Kernel 1: MLP 2 -> 100 -> 100 -> 30 -> 2, one row per thread.
// EXACT R0 69-72us version. FROZEN (see journal).
// Do not touch the dag: FP association is the correctness contract (R5).
// ---------------------------------------------------------------------------
__global__ __launch_bounds__(64, 2) void mlp_kernel(
    const float* __restrict__ x, const float* __restrict__ nd,
    const float* __restrict__ W1, const float* __restrict__ b1,
    const float* __restrict__ W2T, const float* __restrict__ b2,
    const float* __restrict__ W3, const float* __restrict__ b3,
    const float* __restrict__ W4, const float* __restrict__ b4,
    float* __restrict__ outv)
{
    const int r = blockIdx.x * 64 + threadIdx.x;    // 2176*64 = 139264 exact
    const float2 xi = (r < NQ) ? ((const float2*)x)[r]
                               : ((const float2*)nd)[r - NQ];

    // ---- layer 1: h1[100] (constant indices only) ----
    float h1[100];
#pragma unroll
    for (int k = 0; k < 100; ++k)
        h1[k] = fmaxf(fmaf(xi.x, W1[k], fmaf(xi.y, W1[100 + k], b1[k])), 0.0f);

    // ---- layers 2+3 fused: h2j = relu(h1 . W2T[j] + b2[j]) folded into h3
    //      immediately (h2 never materialized); weights all s_load uniform ----
    float h3[30];
#pragma unroll
    for (int jj = 0; jj < 30; ++jj) h3[jj] = b3[jj];

    const float* w2 = W2T;
    const float* w3 = W3;
    for (int j = 0; j < 100; ++j) {
        float a0 = 0.0f, a1 = 0.0f;                 // 2 chains: hide FMA latency
#pragma unroll
        for (int k = 0; k < 100; k += 2) {
            a0 = fmaf(h1[k],     w2[k],     a0);    // w2[k]: s_load scalar
            a1 = fmaf(h1[k + 1], w2[k + 1], a1);
        }
        const float h2j = fmaxf(a0 + a1 + b2[j], 0.0f);
#pragma unroll
        for (int jj = 0; jj < 30; ++jj)
            h3[jj] = fmaf(h2j, w3[jj], h3[jj]);     // w3[jj]: s_load scalar
        w2 += 100;
        w3 += 30;
    }

    // ---- layer 4: 30 -> 2 ----
    float o0 = b4[0], o1 = b4[1];
#pragma unroll
    for (int k = 0; k < 30; ++k) {
        const float h = fmaxf(h3[k], 0.0f);
        o0 = fmaf(h, W4[2 * k],     o0);
        o1 = fmaf(h, W4[2 * k + 1], o1);
    }
    ((float2*)outv)[r] = make_float2(o0, o1);
}

// ---------------------------------------------------------------------------
// Kernel 2: per-internal-node stop-branch class mixture (query-independent).
// Verbatim (passed every round).
// ---------------------------------------------------------------------------
__global__ __launch_bounds__(256) void prob2_kernel(
    const float2* __restrict__ emb, const float2* __restrict__ cls,
    float2* __restrict__ p2)
{
    const int i = blockIdx.x * 256 + threadIdx.x;   // 0..1023
    const float2 ei = emb[i];
    const int base = 8 * i + 1;

    float d2[8];
    float m2 = BIGD;
#pragma unroll
    for (int j = 0; j < 8; ++j) {
        const int c = base + j;
        const bool v = c < MN;
        const float2 ec = emb[v ? c : 0];
        const float dx = ei.x - ec.x + EPSD;
        const float dy = ei.y - ec.y + EPSD;
        d2[j] = v ? sqrtf(dx * dx + dy * dy) : BIGD;
        m2 = fminf(m2, d2[j]);
    }
    float s2 = 0.0f, mix0 = 0.0f, mix1 = 0.0f;
#pragma unroll
    for (int j = 0; j < 8; ++j) {
        const float w = expf(m2 - d2[j]);   // exactly 0 for pads
        s2 += w;
        const int c = base + j;
        if (c < MN) {
            const float2 cv = cls[c];
            mix0 = fmaf(w, cv.x, mix0);
            mix1 = fmaf(w, cv.y, mix1);
        }
    }
    mix0 /= s2;
    mix1 /= s2;
    p2[i] = make_float2(logf(fmaxf(mix0, 1e-30f)),
                        logf(fmaxf(mix1, 1e-30f)));
}

// ---------------------------------------------------------------------------
// Kernel 3: per-query traversal (R3/R12 shape: LDS-staged emb with
// bank-decorrelated layout + sp2). d0 carried across steps, verbatim.
// ---------------------------------------------------------------------------
#define SEMB_F (2 * MN + MN / 8)    // 17408 floats = 68 KB

__global__ __launch_bounds__(256) void traverse_kernel(
    const float* __restrict__ qx, const float2* __restrict__ emb,
    const float2* __restrict__ p2g, float* __restrict__ out)
{
    __shared__ float sembf[SEMB_F];  // 68 KB, padded layout
    __shared__ float2 sp2[NINT];     // 8 KB
    {
        for (int c = threadIdx.x; c < MN; c += 256) {   // coalesced 8B/lane
            const float2 e = emb[c];
            const int off = 2 * c + (c >> 3);
            sembf[off]     = e.x;
            sembf[off + 1] = e.y;
        }
        const float4* gp = (const float4*)p2g;
        float4* sp = (float4*)sp2;
#pragma unroll
        for (int t = 0; t < 2; ++t)
            sp[threadIdx.x + 256 * t] = gp[threadIdx.x + 256 * t];
    }
    __syncthreads();

    const int qi = blockIdx.x * 256 + threadIdx.x;  // grid = NQ/256
    const float2 qv = ((const float2*)qx)[qi];

    int cur = 0;
    float d0;
    {
        const float ex = sembf[0], ey = sembf[1];   // node 0 at offset 0
        const float dx = ex - qv.x + EPSD;
        const float dy = ey - qv.y + EPSD;
        d0 = sqrtf(dx * dx + dy * dy);
    }
    float prob = 0.0f, out0 = 0.0f, out1 = 0.0f;
    bool done = false;

    for (int t = 0; t < DEPTHT; ++t) {
        if (__all(done)) break;
        if (!done) {
            const int base = 8 * cur + 1;
            const int boff = 17 * cur + 2;          // float offset of child 0

            float dc[8];
#pragma unroll
            for (int j = 0; j < 8; ++j) {
                const int c = base + j;
                const bool v = c < MN;
                const int off = v ? (boff + 2 * j + (j == 7 ? 1 : 0)) : 0;
                const float ex = sembf[off];
                const float ey = sembf[off + 1];
                const float dx = ex - qv.x + EPSD;
                const float dy = ey - qv.y + EPSD;
                dc[j] = v ? sqrtf(dx * dx + dy * dy) : BIGD;
            }

            // argmax(log_softmax(-d)) == first argmin(d)
            float dmin = d0;
            int amax = 0;
#pragma unroll
            for (int j = 0; j < 8; ++j)
                if (dc[j] < dmin) { dmin = dc[j]; amax = j + 1; }

            float s = expf(dmin - d0);
#pragma unroll
            for (int j = 0; j < 8; ++j) s += expf(dmin - dc[j]);
            const float max_prob = -logf(s);
            // quirk: t==0 adds max_prob twice
            const float prob_new = prob + max_prob + ((t == 0) ? max_prob : 0.0f);

            if (amax == 0) {
                if (base < MN) {                  // internal node
                    const float2 pp = sp2[cur];
                    out0 = prob_new + pp.x;
                    out1 = prob_new + pp.y;
                } else {                          // leaf
                    out0 = prob_new;
                    out1 = prob_new;
                }
                done = true;
            } else {
                cur  = base + amax - 1;
                d0   = dmin;                      // child dist == next d0
                prob = prob_new;
            }
        }
    }

    ((float2*)out)[qi] = make_float2(out0, out1);
}

// ---------------------------------------------------------------------------
extern "C" void kernel_launch(void* const* d_in, const int* in_sizes, int n_in,
                              void* d_out, int out_size, void* d_ws, size_t ws_size,
                              hipStream_t stream)
{
    const float* x   = (const float*)d_in[0];
    const float* nd  = (const float*)d_in[1];
    const float* cls = (const float*)d_in[2];
    // d_in[3] (children) unused: complete 8-ary tree, child = 8i+1+j if <8192
    const float* W1 = (const float*)d_in[4];
    const float* b1 = (const float*)d_in[5];
    const float* W2 = (const float*)d_in[6];
    const float* b2 = (const float*)d_in[7];
    const float* W3 = (const float*)d_in[8];
    const float* b3 = (const float*)d_in[9];
    const float* W4 = (const float*)d_in[10];
    const float* b4 = (const float*)d_in[11];

    float* ws   = (float*)d_ws;
    float* qx   = ws;                        // [NQ][2]
    float* embf = ws + 2 * NQ;               // [MN][2]
    float* p2f  = ws + 2 * (NQ + MN);        // [NINT][2]
    float* w2t  = p2f + 2 * NINT;            // [100][100]

    transpose_w2<<<40, 256, 0, stream>>>(W2, w2t);

    mlp_kernel<<<(NQ + MN) / 64, 64, 0, stream>>>(
        x, nd, W1, b1, w2t, b2, W3, b3, W4, b4, qx);

    prob2_kernel<<<NINT / 256, 256, 0, stream>>>(
        (const float2*)embf, (const float2*)cls, (float2*)p2f);

    traverse_kernel<<<NQ / 256, 256, 0, stream>>>(
        qx, (const float2*)embf, (const float2*)p2f, (float*)d_out);
}